// Round 1
// baseline (45.100 us; speedup 1.0000x reference)
//
#include <hip/hip_runtime.h>

#define T1 1024
#define T2 256

__device__ __forceinline__ float wave_sum(float v){
    #pragma unroll
    for (int off=32; off; off>>=1) v += __shfl_down(v, off, 64);
    return v;
}

// Kernel 1: per-a slice (14 blocks). Stages i (3->20->100), c (10->8->1), s (17->34->17).
// Produces h[a][b][d] = [14][17][100] in global ws.
__global__ __launch_bounds__(T1) void k_stage1(
    const float* __restrict__ x,
    const float* __restrict__ iW1, const float* __restrict__ ib1,
    const float* __restrict__ ig,  const float* __restrict__ iB,
    const float* __restrict__ iW2, const float* __restrict__ ib2,
    const float* __restrict__ cW1, const float* __restrict__ cb1,
    const float* __restrict__ cg,  const float* __restrict__ cB,
    const float* __restrict__ cW2, const float* __restrict__ cb2,
    const float* __restrict__ sW1, const float* __restrict__ sb1,
    const float* __restrict__ sg,  const float* __restrict__ sB,
    const float* __restrict__ sW2, const float* __restrict__ sb2,
    float* __restrict__ h_out)
{
    const int a = blockIdx.x;
    const int t = threadIdx.x;
    __shared__ float u[170][20];       // stage-i hidden, activated
    __shared__ float h1[17][10][100];  // stage-i output
    __shared__ float h2[17][100];      // stage-c output
    __shared__ float spre[100][34];    // stage-s hidden

    // Phase A: stage-i first linear + LN + relu, one thread per row r=(b,c)
    if (t < 170) {
        const float* xr = x + (a*170 + t)*3;
        float x0 = xr[0], x1 = xr[1], x2 = xr[2];
        float pre[20];
        float mu = 0.f;
        #pragma unroll
        for (int j = 0; j < 20; ++j) {
            float v = ib1[j] + x0*iW1[j] + x1*iW1[20+j] + x2*iW1[40+j];
            pre[j] = v; mu += v;
        }
        mu *= 0.05f;
        float var = 0.f;
        #pragma unroll
        for (int j = 0; j < 20; ++j) { float d = pre[j]-mu; var = fmaf(d,d,var); }
        float inv = rsqrtf(var*0.05f + 1e-5f);
        #pragma unroll
        for (int j = 0; j < 20; ++j) {
            float v = (pre[j]-mu)*inv*ig[j] + iB[j];
            u[t][j] = v > 0.f ? v : 0.f;
        }
    }
    __syncthreads();

    // Phase B: stage-i second linear: 170x100 outputs, 20 MACs each
    for (int o = t; o < 17000; o += T1) {
        int r = o / 100, d = o - 100*r;
        float acc = ib2[d];
        #pragma unroll
        for (int j = 0; j < 20; ++j) acc = fmaf(u[r][j], iW2[j*100+d], acc);
        ((float*)h1)[o] = acc;
    }
    __syncthreads();

    // Phase C: stage c (10->8->1) per (b,d), serial per thread
    for (int o = t; o < 1700; o += T1) {
        int b = o / 100, d = o - 100*b;
        float w[8];
        #pragma unroll
        for (int j = 0; j < 8; ++j) w[j] = cb1[j];
        #pragma unroll
        for (int c = 0; c < 10; ++c) {
            float v = h1[b][c][d];
            #pragma unroll
            for (int j = 0; j < 8; ++j) w[j] = fmaf(v, cW1[c*8+j], w[j]);
        }
        float mu = 0.f;
        #pragma unroll
        for (int j = 0; j < 8; ++j) mu += w[j];
        mu *= 0.125f;
        float var = 0.f;
        #pragma unroll
        for (int j = 0; j < 8; ++j) { float d2 = w[j]-mu; var = fmaf(d2,d2,var); }
        float inv = rsqrtf(var*0.125f + 1e-5f);
        float acc = cb2[0];
        #pragma unroll
        for (int j = 0; j < 8; ++j) {
            float v = (w[j]-mu)*inv*cg[j] + cB[j];
            v = v > 0.f ? v : 0.f;
            acc = fmaf(v, cW2[j], acc);
        }
        h2[b][d] = acc;
    }
    __syncthreads();

    // Phase D: stage-s first linear: (d,j) 100x34 outputs, 17 MACs each
    for (int o = t; o < 3400; o += T1) {
        int d = o / 34, j = o - 34*d;
        float acc = sb1[j];
        #pragma unroll
        for (int b = 0; b < 17; ++b) acc = fmaf(h2[b][d], sW1[b*34+j], acc);
        spre[d][j] = acc;
    }
    __syncthreads();

    // Phase E: LN(34) + relu per d-row
    if (t < 100) {
        float mu = 0.f;
        #pragma unroll
        for (int j = 0; j < 34; ++j) mu += spre[t][j];
        mu *= (1.f/34.f);
        float var = 0.f;
        #pragma unroll
        for (int j = 0; j < 34; ++j) { float d = spre[t][j]-mu; var = fmaf(d,d,var); }
        float inv = rsqrtf(var*(1.f/34.f) + 1e-5f);
        #pragma unroll
        for (int j = 0; j < 34; ++j) {
            float v = (spre[t][j]-mu)*inv*sg[j] + sB[j];
            spre[t][j] = v > 0.f ? v : 0.f;
        }
    }
    __syncthreads();

    // Phase F: stage-s second linear, write transposed: h_out[a][b2][d]
    for (int o = t; o < 1700; o += T1) {
        int d = o / 17, b2 = o - 17*d;
        float acc = sb2[b2];
        #pragma unroll
        for (int j = 0; j < 34; ++j) acc = fmaf(spre[d][j], sW2[j*17+b2], acc);
        h_out[a*1700 + b2*100 + d] = acc;
    }
}

// Kernel 2: per (frame f in 0..11, b in 0..16) = 204 blocks.
// f<10: full m/n -> t -> k chain then p. f>=10: p on zero row.
__global__ __launch_bounds__(T2) void k_stage2(
    const float* __restrict__ h,
    const float* __restrict__ mW1, const float* __restrict__ mb1,
    const float* __restrict__ mg,  const float* __restrict__ mB,
    const float* __restrict__ mW2, const float* __restrict__ mb2,
    const float* __restrict__ nW1, const float* __restrict__ nb1,
    const float* __restrict__ ng,  const float* __restrict__ nB,
    const float* __restrict__ nW2, const float* __restrict__ nb2,
    const float* __restrict__ tW1, const float* __restrict__ tb1,
    const float* __restrict__ tg,  const float* __restrict__ tB,
    const float* __restrict__ tW2, const float* __restrict__ tb2,
    const float* __restrict__ kW1, const float* __restrict__ kb1,
    const float* __restrict__ kg,  const float* __restrict__ kB,
    const float* __restrict__ kW2, const float* __restrict__ kb2,
    const float* __restrict__ pW1, const float* __restrict__ pb1,
    const float* __restrict__ pg,  const float* __restrict__ pB,
    const float* __restrict__ pW2, const float* __restrict__ pb2,
    float* __restrict__ out)
{
    const int blk = blockIdx.x;
    const int f = blk / 17, b = blk % 17;
    const int t = threadIdx.x;
    const bool full = (f < 10);

    __shared__ float inrow[5][100];   // 0:dA=h[f+1]-h[f] 1:hA=h[f+1] 2:dC=h[f+4]-h[f+3] 3:hD=h[f+3] 4:hE=h[f+2]
    __shared__ float hid4[4][20];     // m(dA), n(hA), m(dC), n(hD) hidden
    __shared__ float v4[4][100];      // mf, pf0, mb, nf0
    __shared__ float hidT[2][20];
    __shared__ float tv[2][100];      // pf, nf
    __shared__ float kpre[100];
    __shared__ float khid[100];
    __shared__ float comb[100];
    __shared__ float ppre[30];
    __shared__ float pact[30];
    __shared__ float red[4];
    __shared__ float stats[2];

    if (full) {
        const float* hb = h + b*100;
        for (int o = t; o < 100; o += T2) {
            float h0  = hb[(f  )*1700 + o];
            float h1v = hb[(f+1)*1700 + o];
            float h2v = hb[(f+2)*1700 + o];
            float h3v = hb[(f+3)*1700 + o];
            float h4v = hb[(f+4)*1700 + o];
            inrow[0][o] = h1v - h0;
            inrow[1][o] = h1v;
            inrow[2][o] = h4v - h3v;
            inrow[3][o] = h3v;
            inrow[4][o] = h2v;
        }
        __syncthreads();

        // m/n first linear: 4 rows x 20 hidden, 100 MACs each (4 accumulators)
        if (t < 80) {
            int which = t / 20, jj = t - 20*which;
            bool is_m = (which == 0) || (which == 2);
            const float* W1 = is_m ? mW1 : nW1;
            const float* B1 = is_m ? mb1 : nb1;
            const float* in = inrow[which];
            float a0=0,a1=0,a2=0,a3=0;
            for (int e = 0; e < 100; e += 4) {
                a0 = fmaf(in[e+0], W1[(e+0)*20+jj], a0);
                a1 = fmaf(in[e+1], W1[(e+1)*20+jj], a1);
                a2 = fmaf(in[e+2], W1[(e+2)*20+jj], a2);
                a3 = fmaf(in[e+3], W1[(e+3)*20+jj], a3);
            }
            hid4[which][jj] = B1[jj] + ((a0+a1)+(a2+a3));
        }
        __syncthreads();

        // LN(20)+relu for the 4 hidden rows
        if (t < 4) {
            bool is_m = (t == 0) || (t == 2);
            const float* g  = is_m ? mg : ng;
            const float* Bv = is_m ? mB : nB;
            float mu = 0.f;
            #pragma unroll
            for (int j = 0; j < 20; ++j) mu += hid4[t][j];
            mu *= 0.05f;
            float var = 0.f;
            #pragma unroll
            for (int j = 0; j < 20; ++j) { float d = hid4[t][j]-mu; var = fmaf(d,d,var); }
            float inv = rsqrtf(var*0.05f + 1e-5f);
            #pragma unroll
            for (int j = 0; j < 20; ++j) {
                float v = (hid4[t][j]-mu)*inv*g[j] + Bv[j];
                hid4[t][j] = v > 0.f ? v : 0.f;
            }
        }
        __syncthreads();

        // m/n second linear: 4 x 100 outputs, 20 MACs each
        for (int o = t; o < 400; o += T2) {
            int which = o / 100, d = o - 100*which;
            bool is_m = (which == 0) || (which == 2);
            const float* W2 = is_m ? mW2 : nW2;
            const float* B2 = is_m ? mb2 : nb2;
            float acc = B2[d];
            #pragma unroll
            for (int j = 0; j < 20; ++j) acc = fmaf(hid4[which][j], W2[j*100+d], acc);
            v4[which][d] = acc;
        }
        __syncthreads();

        // t first linear: 2 rows x 20 hidden, 200 MACs each
        if (t < 40) {
            int which = t / 20, jj = t - 20*which;
            const float* inA = which ? v4[3] : v4[1];   // n output first in concat
            const float* inB = which ? v4[2] : v4[0];   // m output second
            float a0=0,a1=0,a2=0,a3=0;
            for (int e = 0; e < 100; e += 4) {
                a0 = fmaf(inA[e+0], tW1[(e+0)*20+jj], a0);
                a1 = fmaf(inA[e+1], tW1[(e+1)*20+jj], a1);
                a2 = fmaf(inA[e+2], tW1[(e+2)*20+jj], a2);
                a3 = fmaf(inA[e+3], tW1[(e+3)*20+jj], a3);
            }
            for (int e = 0; e < 100; e += 4) {
                a0 = fmaf(inB[e+0], tW1[(100+e+0)*20+jj], a0);
                a1 = fmaf(inB[e+1], tW1[(100+e+1)*20+jj], a1);
                a2 = fmaf(inB[e+2], tW1[(100+e+2)*20+jj], a2);
                a3 = fmaf(inB[e+3], tW1[(100+e+3)*20+jj], a3);
            }
            hidT[which][jj] = tb1[jj] + ((a0+a1)+(a2+a3));
        }
        __syncthreads();

        if (t < 2) {
            float mu = 0.f;
            #pragma unroll
            for (int j = 0; j < 20; ++j) mu += hidT[t][j];
            mu *= 0.05f;
            float var = 0.f;
            #pragma unroll
            for (int j = 0; j < 20; ++j) { float d = hidT[t][j]-mu; var = fmaf(d,d,var); }
            float inv = rsqrtf(var*0.05f + 1e-5f);
            #pragma unroll
            for (int j = 0; j < 20; ++j) {
                float v = (hidT[t][j]-mu)*inv*tg[j] + tB[j];
                hidT[t][j] = v > 0.f ? v : 0.f;
            }
        }
        __syncthreads();

        // t second linear: 2 x 100, 20 MACs each
        for (int o = t; o < 200; o += T2) {
            int which = o / 100, d = o - 100*which;
            float acc = tb2[d];
            #pragma unroll
            for (int j = 0; j < 20; ++j) acc = fmaf(hidT[which][j], tW2[j*100+d], acc);
            tv[which][d] = acc;
        }
        __syncthreads();

        // k first linear: 100 outputs x 300 MACs (concat [pf, hE, nf])
        if (t < 100) {
            const float* i0 = tv[0];
            const float* i1 = inrow[4];
            const float* i2 = tv[1];
            float a0=0,a1=0,a2=0,a3=0;
            for (int e = 0; e < 100; e += 4) {
                a0 = fmaf(i0[e+0], kW1[(e+0)*100+t], a0);
                a1 = fmaf(i0[e+1], kW1[(e+1)*100+t], a1);
                a2 = fmaf(i0[e+2], kW1[(e+2)*100+t], a2);
                a3 = fmaf(i0[e+3], kW1[(e+3)*100+t], a3);
            }
            for (int e = 0; e < 100; e += 4) {
                a0 = fmaf(i1[e+0], kW1[(100+e+0)*100+t], a0);
                a1 = fmaf(i1[e+1], kW1[(100+e+1)*100+t], a1);
                a2 = fmaf(i1[e+2], kW1[(100+e+2)*100+t], a2);
                a3 = fmaf(i1[e+3], kW1[(100+e+3)*100+t], a3);
            }
            for (int e = 0; e < 100; e += 4) {
                a0 = fmaf(i2[e+0], kW1[(200+e+0)*100+t], a0);
                a1 = fmaf(i2[e+1], kW1[(200+e+1)*100+t], a1);
                a2 = fmaf(i2[e+2], kW1[(200+e+2)*100+t], a2);
                a3 = fmaf(i2[e+3], kW1[(200+e+3)*100+t], a3);
            }
            kpre[t] = kb1[t] + ((a0+a1)+(a2+a3));
        }
        __syncthreads();

        // LN(100) via wave reduce
        {
            float v = (t < 100) ? kpre[t] : 0.f;
            v = wave_sum(v);
            if ((t & 63) == 0) red[t >> 6] = v;
            __syncthreads();
            if (t == 0) stats[0] = (red[0]+red[1]+red[2]+red[3]) * 0.01f;
            __syncthreads();
            float mu = stats[0];
            float d2 = 0.f;
            if (t < 100) { float d = kpre[t]-mu; d2 = d*d; }
            d2 = wave_sum(d2);
            if ((t & 63) == 0) red[t >> 6] = d2;
            __syncthreads();
            if (t == 0) stats[1] = rsqrtf((red[0]+red[1]+red[2]+red[3])*0.01f + 1e-5f);
            __syncthreads();
            float inv = stats[1];
            if (t < 100) {
                float val = (kpre[t]-mu)*inv*kg[t] + kB[t];
                khid[t] = val > 0.f ? val : 0.f;
            }
        }
        __syncthreads();

        // k second linear: 100 outputs x 100 MACs
        if (t < 100) {
            float a0=0,a1=0,a2=0,a3=0;
            for (int j = 0; j < 100; j += 4) {
                a0 = fmaf(khid[j+0], kW2[(j+0)*100+t], a0);
                a1 = fmaf(khid[j+1], kW2[(j+1)*100+t], a1);
                a2 = fmaf(khid[j+2], kW2[(j+2)*100+t], a2);
                a3 = fmaf(khid[j+3], kW2[(j+3)*100+t], a3);
            }
            comb[t] = kb2[t] + ((a0+a1)+(a2+a3));
        }
        __syncthreads();
    } else {
        for (int o = t; o < 100; o += T2) comb[o] = 0.f;
        __syncthreads();
    }

    // p stage (all blocks): 100 -> 30 (LN) -> 3
    if (t < 30) {
        float a0=0,a1=0,a2=0,a3=0;
        for (int e = 0; e < 100; e += 4) {
            a0 = fmaf(comb[e+0], pW1[(e+0)*30+t], a0);
            a1 = fmaf(comb[e+1], pW1[(e+1)*30+t], a1);
            a2 = fmaf(comb[e+2], pW1[(e+2)*30+t], a2);
            a3 = fmaf(comb[e+3], pW1[(e+3)*30+t], a3);
        }
        ppre[t] = pb1[t] + ((a0+a1)+(a2+a3));
    }
    __syncthreads();
    if (t == 0) {
        float mu = 0.f;
        #pragma unroll
        for (int j = 0; j < 30; ++j) mu += ppre[j];
        mu *= (1.f/30.f);
        float var = 0.f;
        #pragma unroll
        for (int j = 0; j < 30; ++j) { float d = ppre[j]-mu; var = fmaf(d,d,var); }
        stats[0] = mu;
        stats[1] = rsqrtf(var*(1.f/30.f) + 1e-5f);
    }
    __syncthreads();
    if (t < 30) {
        float v = (ppre[t]-stats[0])*stats[1]*pg[t] + pB[t];
        pact[t] = v > 0.f ? v : 0.f;
    }
    __syncthreads();
    if (t < 3) {
        float acc = pb2[t];
        #pragma unroll
        for (int j = 0; j < 30; ++j) acc = fmaf(pact[j], pW2[j*3+t], acc);
        out[(f*17 + b)*3 + t] = acc;
    }
}

extern "C" void kernel_launch(void* const* d_in, const int* in_sizes, int n_in,
                              void* d_out, int out_size, void* d_ws, size_t ws_size,
                              hipStream_t stream) {
    const float* x = (const float*)d_in[0];
    float* h = (float*)d_ws;  // [14][17][100] = 23800 floats
    #define P(i) ((const float*)d_in[i])
    k_stage1<<<14, T1, 0, stream>>>(x,
        P(1), P(2), P(3), P(4), P(5), P(6),
        P(7), P(8), P(9), P(10), P(11), P(12),
        P(13), P(14), P(15), P(16), P(17), P(18),
        h);
    k_stage2<<<204, T2, 0, stream>>>(h,
        P(19), P(20), P(21), P(22), P(23), P(24),
        P(25), P(26), P(27), P(28), P(29), P(30),
        P(31), P(32), P(33), P(34), P(35), P(36),
        P(37), P(38), P(39), P(40), P(41), P(42),
        P(43), P(44), P(45), P(46), P(47), P(48),
        (float*)d_out);
    #undef P
}